// Round 9
// baseline (2056.056 us; speedup 1.0000x reference)
//
#include <hip/hip_runtime.h>

typedef unsigned short ushortT;
typedef short bf16x8 __attribute__((ext_vector_type(8)));
typedef float f32x4 __attribute__((ext_vector_type(4)));
typedef unsigned int u32x4 __attribute__((ext_vector_type(4)));

// EqProp free phase, B=4096, layers [10,512,512 | x=784 clamped], T=30, DT=0.5.
// States stay in [0,1] => rho(s)=s, rhop(s)=1.
// State: bf16 plane, row stride 1056: [0,10)=s0, [32,544)=s1, [544,1056)=s2.
// Persistent k_loop3: 256 blocks x 256 thr (1 block/CU guaranteed co-resident:
// grid <= #CUs at any occupancy). Each wave holds its W1 hi/lo slice (32 cols x
// K=512) in 256 VGPRs across all steps -> weight traffic eliminated WITHOUT
// relying on caches the inter-step fence invalidates. A-window shared via 24KB
// static LDS. Two-level grid barrier (per-XCD lines) in ws.
// Numerics identical to proven R6 scheme (absmax 0.0117).
#define HSTR 1056
#define OFF1B 32
#define OFF2B 544
#define CSTR 1034

__device__ __forceinline__ ushortT f2b(float f) {
    union { float f; unsigned u; } v; v.f = f;
    return (ushortT)((v.u + 0x7FFFu + ((v.u >> 16) & 1u)) >> 16);  // RNE
}
__device__ __forceinline__ float b2f(ushortT b) {
    union { unsigned u; float f; } v; v.u = ((unsigned)b) << 16;
    return v.f;
}
__device__ __forceinline__ void split2(float f, ushortT& h, ushortT& l) {
    h = f2b(f);
    l = f2b(f - b2f(h));
}

#define MFMA(a, b, c) __builtin_amdgcn_mfma_f32_16x16x32_bf16(a, b, c, 0, 0, 0)
#define BCAST(x) __builtin_bit_cast(bf16x8, x)

// ---------------- zero state buffer A + barrier words ----------------
__global__ void k_zero(u32x4* __restrict__ p, int n, unsigned* __restrict__ bar) {
    u32x4 z = {0u, 0u, 0u, 0u};
    for (int i = blockIdx.x * blockDim.x + threadIdx.x; i < n; i += gridDim.x * blockDim.x)
        p[i] = z;
    for (int i = blockIdx.x * blockDim.x + threadIdx.x; i < 1024; i += gridDim.x * blockDim.x)
        bar[i] = 0u;
}

// ---------------- W1 -> split bf16 hi/lo, row-major + transpose (proven) ------------
__global__ __launch_bounds__(256) void k_prep(const float* __restrict__ W1,
                                              ushortT* __restrict__ W1h,
                                              ushortT* __restrict__ W1l,
                                              ushortT* __restrict__ W1Th,
                                              ushortT* __restrict__ W1Tl) {
    __shared__ float tile[64][65];
    const int ti = blockIdx.x >> 3, tj = blockIdx.x & 7;
    const int t = threadIdx.x;
#pragma unroll
    for (int q = 0; q < 16; ++q) {
        int rr = q * 4 + (t >> 6), cc = t & 63;
        float v = W1[(size_t)(ti * 64 + rr) * 512 + tj * 64 + cc];
        tile[rr][cc] = v;
        ushortT h, l; split2(v, h, l);
        W1h[(size_t)(ti * 64 + rr) * 512 + tj * 64 + cc] = h;
        W1l[(size_t)(ti * 64 + rr) * 512 + tj * 64 + cc] = l;
    }
    __syncthreads();
#pragma unroll
    for (int q = 0; q < 16; ++q) {
        int rr = q * 4 + (t >> 6), cc = t & 63;
        ushortT h, l; split2(tile[cc][rr], h, l);
        W1Th[(size_t)(tj * 64 + rr) * 512 + ti * 64 + cc] = h;
        W1Tl[(size_t)(tj * 64 + rr) * 512 + ti * 64 + cc] = l;
    }
}

// ---------------- c2 = rho(x) @ W2^T + b2 via split-bf16 MFMA (proven) ----------------
__global__ __launch_bounds__(256) void k_c2(const float* __restrict__ x,
                                            const float* __restrict__ W2,
                                            const float* __restrict__ b2,
                                            float* __restrict__ c2) {
    __shared__ u32x4 cs[2048];
    u32x4* xHi = cs;
    u32x4* xLo = cs + 512;
    u32x4* wHi = cs + 1024;
    u32x4* wLo = cs + 1536;
    const int bid = blockIdx.x, t = threadIdx.x;
    const int lane = t & 63, w = t >> 6, l15 = lane & 15, l4 = lane >> 4;
    const int bm2 = (bid >> 3) * 64, bn2 = (bid & 7) * 64;
    const int mB2 = (w >> 1) * 32, nB2 = (w & 1) * 32;
    const int sr2 = t >> 2, ub = (t & 3) * 2;
    f32x4 accC[2][2];
#pragma unroll
    for (int i = 0; i < 2; ++i)
#pragma unroll
        for (int j = 0; j < 2; ++j) { f32x4 z = {0.f, 0.f, 0.f, 0.f}; accC[i][j] = z; }
    for (int k0 = 0; k0 < 784; k0 += 64) {
#pragma unroll
        for (int j = 0; j < 2; ++j) {
            int u = ub + j;
            bool valid = (k0 + u * 8 + 8 <= 784);
            union { ushortT us[8]; u32x4 v; } ph, pl, qh, ql;
            if (valid) {
                const float* srcx = x  + (size_t)(bm2 + sr2) * 784 + k0 + u * 8;
                const float* srcw = W2 + (size_t)(bn2 + sr2) * 784 + k0 + u * 8;
#pragma unroll
                for (int e = 0; e < 8; ++e) {
                    float cx = fminf(fmaxf(srcx[e], 0.f), 1.f);
                    split2(cx, ph.us[e], pl.us[e]);
                    split2(srcw[e], qh.us[e], ql.us[e]);
                }
            } else {
#pragma unroll
                for (int e = 0; e < 8; ++e) { ph.us[e]=0; pl.us[e]=0; qh.us[e]=0; ql.us[e]=0; }
            }
            int sw = u ^ (sr2 & 7);
            xHi[sr2 * 8 + sw] = ph.v;  xLo[sr2 * 8 + sw] = pl.v;
            wHi[sr2 * 8 + sw] = qh.v;  wLo[sr2 * 8 + sw] = ql.v;
        }
        __syncthreads();
        int kwMax = (k0 == 768) ? 1 : 2;
        for (int kw = 0; kw < kwMax; ++kw) {
            bf16x8 ah[2], al[2], bh[2], bl[2];
#pragma unroll
            for (int i = 0; i < 2; ++i) {
                int m = mB2 + i * 16 + l15;
                int uu = (kw * 4 + l4) ^ (m & 7);
                ah[i] = BCAST(xHi[m * 8 + uu]);
                al[i] = BCAST(xLo[m * 8 + uu]);
                int n = nB2 + i * 16 + l15;
                int uv = (kw * 4 + l4) ^ (n & 7);
                bh[i] = BCAST(wHi[n * 8 + uv]);
                bl[i] = BCAST(wLo[n * 8 + uv]);
            }
#pragma unroll
            for (int i = 0; i < 2; ++i)
#pragma unroll
                for (int jj = 0; jj < 2; ++jj) {
                    accC[i][jj] = MFMA(ah[i], bh[jj], accC[i][jj]);
                    accC[i][jj] = MFMA(al[i], bh[jj], accC[i][jj]);
                    accC[i][jj] = MFMA(ah[i], bl[jj], accC[i][jj]);
                }
        }
        __syncthreads();
    }
#pragma unroll
    for (int mi = 0; mi < 2; ++mi)
#pragma unroll
        for (int ni = 0; ni < 2; ++ni)
#pragma unroll
            for (int q = 0; q < 4; ++q) {
                int row = bm2 + mB2 + mi * 16 + l4 * 4 + q;
                int col = bn2 + nB2 + ni * 16 + l15;
                c2[(size_t)row * 512 + col] = accC[mi][ni][q] + b2[col];
            }
}

// ================= persistent loop, weights in REGISTERS =================
// 256 blocks x 256 threads. Block: panel(128 rows) x colgroup(128 cols) x role.
// xcd = bid&7; panel = xcd*4 + pp  (all consumers of a panel on one XCD).
__global__ __launch_bounds__(256, 1) void k_loop3(ushortT* __restrict__ hiA,
                                                  ushortT* __restrict__ hiB,
                                                  const ushortT* __restrict__ W1h,
                                                  const ushortT* __restrict__ W1l,
                                                  const ushortT* __restrict__ W1Th,
                                                  const ushortT* __restrict__ W1Tl,
                                                  const float* __restrict__ W0,
                                                  const float* __restrict__ b0,
                                                  const float* __restrict__ b1,
                                                  const float* __restrict__ c2,
                                                  float* __restrict__ outF,
                                                  unsigned* __restrict__ bar) {
    __shared__ u32x4 sA[128 * 4];      // 8 KB: A K=32 window [128 rows][4 units], swizzled
    __shared__ u32x4 auxS[1024];       // 16 KB: z1 -> sA2[0..511] + sB2[512..1023]; z2-cg0 -> sZ0

    const int bid = blockIdx.x, t = threadIdx.x;
    const int lane = t & 63, w = t >> 6, l15 = lane & 15, l4 = lane >> 4;

    const int xcd = bid & 7, idx = bid >> 3;
    const int cg = idx & 3, role = (idx >> 2) & 1, pp = idx >> 3;
    const int panel = xcd * 4 + pp;
    const int bm = panel * 128, bn = cg * 128;
    const bool isZ1 = (role == 0);
    const bool doZ0blk = (!isZ1) && (cg == 0);
    const bool doZ0w = doZ0blk && (w == 0);
    const int colb = bn + w * 32;

    const int aOff = isZ1 ? OFF2B : OFF1B;   // z1 reads s2, z2 reads s1
    const int dOff = isZ1 ? OFF1B : OFF2B;
    const int oOff = isZ1 ? 10 : 522;

    // ---- one-time: this wave's W slice (32 cols x K=512, hi+lo) into 256 VGPRs ----
    const ushortT* __restrict__ Whp = isZ1 ? W1h : W1Th;
    const ushortT* __restrict__ Wlp = isZ1 ? W1l : W1Tl;
    u32x4 wh[2][16], wl[2][16];
#pragma unroll
    for (int ni = 0; ni < 2; ++ni)
#pragma unroll
        for (int kw = 0; kw < 16; ++kw) {
            size_t off = (size_t)(colb + ni * 16 + l15) * 512 + kw * 32 + l4 * 8;
            wh[ni][kw] = *(const u32x4*)(Whp + off);
            wl[ni][kw] = *(const u32x4*)(Wlp + off);
        }

    // ---- one-time aux LDS (synced by first loop barrier) ----
    if (isZ1) {
        if (t < 128) {   // sB2[n][u]: B[n][k] = W0[k][bn+n], K=32 window (10 real)
            int n = t;
#pragma unroll
            for (int u = 0; u < 4; ++u) {
                union { ushortT us[8]; u32x4 v; } pk;
#pragma unroll
                for (int e = 0; e < 8; ++e) {
                    int k = u * 8 + e;
                    pk.us[e] = (k < 10) ? f2b(W0[(size_t)k * 512 + bn + n]) : (ushortT)0;
                }
                auxS[512 + n * 4 + u] = pk.v;
            }
        }
    } else if (doZ0blk) {  // sZ0[c][u]: W0 row-major, 16 rows (6 zero-pad) x K=512, swizzled
        int c = t >> 4, u0 = (t & 15) * 4;
#pragma unroll
        for (int j = 0; j < 4; ++j) {
            int U = u0 + j;
            union { ushortT us[8]; u32x4 v; } pk;
#pragma unroll
            for (int e = 0; e < 8; ++e)
                pk.us[e] = (c < 10) ? f2b(W0[(size_t)c * 512 + U * 8 + e]) : (ushortT)0;
            auxS[c * 64 + (U ^ (c & 7))] = pk.v;
        }
    }

    float b1r[2];
#pragma unroll
    for (int ni = 0; ni < 2; ++ni) b1r[ni] = isZ1 ? b1[colb + ni * 16 + l15] : 0.f;
    const float b0v = (doZ0w && l15 < 10) ? b0[l15] : 0.f;

    const int sr = t >> 1, su = (t & 1) * 2;   // A staging: 2 thr/row, 2 units each

    for (int ts = 0; ts < 30; ++ts) {
        const ushortT* __restrict__ sH = (ts & 1) ? hiB : hiA;
        ushortT* __restrict__ dH       = (ts & 1) ? hiA : hiB;
        const bool fin = (ts == 29);

        f32x4 acc[8][2];
#pragma unroll
        for (int mi = 0; mi < 8; ++mi)
#pragma unroll
            for (int ni = 0; ni < 2; ++ni) { f32x4 z = {0.f,0.f,0.f,0.f}; acc[mi][ni] = z; }
        f32x4 accZ[8];
#pragma unroll
        for (int mi = 0; mi < 8; ++mi) { f32x4 z = {0.f,0.f,0.f,0.f}; accZ[mi] = z; }

        if (isZ1 && t < 128) {   // sA2: s0 window (10 real, pad to K=32)
            union { ushortT us[16]; u32x4 v2[2]; } pk;
#pragma unroll
            for (int e = 0; e < 16; ++e) pk.us[e] = 0;
            const ushortT* sp = sH + (size_t)(bm + t) * HSTR;
#pragma unroll
            for (int e = 0; e < 10; ++e) pk.us[e] = sp[e];
            u32x4 z = {0u, 0u, 0u, 0u};
            auxS[t * 4 + 0] = pk.v2[0];
            auxS[t * 4 + 1] = pk.v2[1];
            auxS[t * 4 + 2] = z;
            auxS[t * 4 + 3] = z;
        }

        // ---- K loop: 16 windows of K=32; W from registers, A via LDS ----
        u32x4 tA[2];
        {
            const u32x4* gA = (const u32x4*)(sH + (size_t)(bm + sr) * HSTR + aOff);
            tA[0] = gA[su];  tA[1] = gA[su + 1];
        }
#pragma unroll
        for (int it = 0; it < 16; ++it) {
            __syncthreads();                      // prev compute done; sA reusable
            sA[sr * 4 + ( su      ^ (sr & 3))] = tA[0];
            sA[sr * 4 + ((su + 1) ^ (sr & 3))] = tA[1];
            if (it < 15) {
                const u32x4* gA = (const u32x4*)(sH + (size_t)(bm + sr) * HSTR + aOff + (it + 1) * 32);
                tA[0] = gA[su];  tA[1] = gA[su + 1];
            }
            __syncthreads();                      // publish window
            bf16x8 a[8];
#pragma unroll
            for (int mi = 0; mi < 8; ++mi) {
                int m = mi * 16 + l15;
                a[mi] = BCAST(sA[m * 4 + (l4 ^ (m & 3))]);
            }
#pragma unroll
            for (int mi = 0; mi < 8; ++mi) {
                acc[mi][0] = MFMA(a[mi], BCAST(wh[0][it]), acc[mi][0]);
                acc[mi][0] = MFMA(a[mi], BCAST(wl[0][it]), acc[mi][0]);
                acc[mi][1] = MFMA(a[mi], BCAST(wh[1][it]), acc[mi][1]);
                acc[mi][1] = MFMA(a[mi], BCAST(wl[1][it]), acc[mi][1]);
            }
            if (doZ0w) {
                bf16x8 bz = BCAST(auxS[l15 * 64 + ((it * 4 + l4) ^ (l15 & 7))]);
#pragma unroll
                for (int mi = 0; mi < 8; ++mi)
                    accZ[mi] = MFMA(a[mi], bz, accZ[mi]);
            }
        }
        if (isZ1) {   // s0 @ W0 extra K=32 window
            bf16x8 bb0 = BCAST(auxS[512 + (size_t)(w * 32 + l15) * 4 + l4]);
            bf16x8 bb1 = BCAST(auxS[512 + (size_t)(w * 32 + 16 + l15) * 4 + l4]);
#pragma unroll
            for (int mi = 0; mi < 8; ++mi) {
                bf16x8 a2 = BCAST(auxS[(mi * 16 + l15) * 4 + l4]);
                acc[mi][0] = MFMA(a2, bb0, acc[mi][0]);
                acc[mi][1] = MFMA(a2, bb1, acc[mi][1]);
            }
        }

        // ---- epilogue: v = clip(0.5*old + 0.5*(acc + bias)) ----
#pragma unroll
        for (int mi = 0; mi < 8; ++mi) {
#pragma unroll
            for (int ni = 0; ni < 2; ++ni) {
                int gc = colb + ni * 16 + l15;
#pragma unroll
                for (int q = 0; q < 4; ++q) {
                    size_t row = (size_t)bm + mi * 16 + l4 * 4 + q;
                    float bias = isZ1 ? b1r[ni] : c2[row * 512 + gc];
                    float old = b2f(sH[row * HSTR + dOff + gc]);
                    float v = 0.5f * old + 0.5f * (acc[mi][ni][q] + bias);
                    v = fminf(fmaxf(v, 0.f), 1.f);
                    if (fin) outF[row * CSTR + oOff + gc] = v;
                    else     dH[row * HSTR + dOff + gc] = f2b(v);
                }
            }
        }
        if (doZ0w && l15 < 10) {
#pragma unroll
            for (int mi = 0; mi < 8; ++mi) {
#pragma unroll
                for (int q = 0; q < 4; ++q) {
                    size_t row = (size_t)bm + mi * 16 + l4 * 4 + q;
                    float old = b2f(sH[row * HSTR + l15]);
                    float v = 0.5f * old + 0.5f * (accZ[mi][q] + b0v);
                    v = fminf(fmaxf(v, 0.f), 1.f);
                    if (fin) outF[row * CSTR + l15] = v;
                    else     dH[row * HSTR + l15] = f2b(v);
                }
            }
        }

        // ---- two-level grid barrier (32 arrivals/XCD line -> 8 -> per-XCD gen) ----
        if (!fin) {
            __syncthreads();
            if (t == 0) {
                unsigned prev = __hip_atomic_fetch_add(&bar[xcd * 32], 1u,
                                    __ATOMIC_ACQ_REL, __HIP_MEMORY_SCOPE_AGENT);
                if (prev == 31u) {
                    __hip_atomic_store(&bar[xcd * 32], 0u,
                                       __ATOMIC_RELAXED, __HIP_MEMORY_SCOPE_AGENT);
                    unsigned p2 = __hip_atomic_fetch_add(&bar[256], 1u,
                                    __ATOMIC_ACQ_REL, __HIP_MEMORY_SCOPE_AGENT);
                    if (p2 == 7u) {
                        __hip_atomic_store(&bar[256], 0u,
                                           __ATOMIC_RELAXED, __HIP_MEMORY_SCOPE_AGENT);
                        for (int x2 = 0; x2 < 8; ++x2)
                            __hip_atomic_store(&bar[320 + x2 * 32], (unsigned)(ts + 1),
                                               __ATOMIC_RELEASE, __HIP_MEMORY_SCOPE_AGENT);
                    }
                }
                while (__hip_atomic_load(&bar[320 + xcd * 32],
                                         __ATOMIC_RELAXED, __HIP_MEMORY_SCOPE_AGENT)
                       < (unsigned)(ts + 1))
                    __builtin_amdgcn_s_sleep(2);
                (void)__hip_atomic_load(&bar[320 + xcd * 32],
                                        __ATOMIC_ACQUIRE, __HIP_MEMORY_SCOPE_AGENT);
            }
            __syncthreads();
        }
    }
}

extern "C" void kernel_launch(void* const* d_in, const int* in_sizes, int n_in,
                              void* d_out, int out_size, void* d_ws, size_t ws_size,
                              hipStream_t stream) {
    const float* x  = (const float*)d_in[3];
    const float* W0 = (const float*)d_in[4];
    const float* b0 = (const float*)d_in[5];
    const float* W1 = (const float*)d_in[6];
    const float* b1 = (const float*)d_in[7];
    const float* W2 = (const float*)d_in[8];
    const float* b2 = (const float*)d_in[9];

    // buffer A in d_out: 4096*1056*2 = 8,650,752 B <= 16,943,104 B
    ushortT* hiA = (ushortT*)d_out;
    // ws: hiB | c2 f32 | W1h | W1l | W1Th | W1Tl | bar (4KB)  (~19.2 MB)
    ushortT* hiB = (ushortT*)d_ws;
    float*   c2  = (float*)(hiB + (size_t)4096 * HSTR);
    ushortT* W1h = (ushortT*)(c2 + (size_t)4096 * 512);
    ushortT* W1l  = W1h + 512 * 512;
    ushortT* W1Th = W1l + 512 * 512;
    ushortT* W1Tl = W1Th + 512 * 512;
    unsigned* bar = (unsigned*)(W1Tl + 512 * 512);

    const int zeroN = (int)((size_t)4096 * HSTR * sizeof(ushortT) / sizeof(u32x4));
    k_zero<<<1024, 256, 0, stream>>>((u32x4*)hiA, zeroN, bar);
    k_prep<<<64, 256, 0, stream>>>(W1, W1h, W1l, W1Th, W1Tl);
    k_c2<<<512, 256, 0, stream>>>(x, W2, b2, c2);

    // no occupancy queries / attribute calls (they fail under graph capture):
    // 256 blocks <= 256 CUs => co-residency structural at any occupancy.
    k_loop3<<<256, 256, 0, stream>>>(hiA, hiB, W1h, W1l, W1Th, W1Tl,
                                     W0, b0, b1, c2, (float*)d_out, bar);
}

// Round 10
// 907.480 us; speedup vs baseline: 2.2657x; 2.2657x over previous
//
#include <hip/hip_runtime.h>

typedef unsigned short ushortT;
typedef short bf16x8 __attribute__((ext_vector_type(8)));
typedef float f32x4 __attribute__((ext_vector_type(4)));
typedef unsigned int u32x4 __attribute__((ext_vector_type(4)));

// EqProp free phase, B=4096, layers [10,512,512 | x=784 clamped], T=30, DT=0.5.
// States stay in [0,1] => rho(s)=s, rhop(s)=1.
// State: bf16 plane, row stride 1056: [0,10)=s0, [32,544)=s1, [544,1056)=s2.
// W1 split hi/lo bf16. 30 launches of k_step3: 1024 blocks (64x64 tiles,
// 4 blocks/CU -> 16 waves/CU) for latency hiding; c2/old/bias prefetched into
// registers before the K loop. Numerics identical to proven R6 (absmax 0.0117).
#define HSTR 1056
#define OFF1B 32
#define OFF2B 544
#define CSTR 1034

__device__ __forceinline__ ushortT f2b(float f) {
    union { float f; unsigned u; } v; v.f = f;
    return (ushortT)((v.u + 0x7FFFu + ((v.u >> 16) & 1u)) >> 16);  // RNE
}
__device__ __forceinline__ float b2f(ushortT b) {
    union { unsigned u; float f; } v; v.u = ((unsigned)b) << 16;
    return v.f;
}
__device__ __forceinline__ void split2(float f, ushortT& h, ushortT& l) {
    h = f2b(f);
    l = f2b(f - b2f(h));
}

#define MFMA(a, b, c) __builtin_amdgcn_mfma_f32_16x16x32_bf16(a, b, c, 0, 0, 0)
#define BCAST(x) __builtin_bit_cast(bf16x8, x)

// ---------------- zero state buffer A ----------------
__global__ void k_zero(u32x4* __restrict__ p, int n) {
    u32x4 z = {0u, 0u, 0u, 0u};
    for (int i = blockIdx.x * blockDim.x + threadIdx.x; i < n; i += gridDim.x * blockDim.x)
        p[i] = z;
}

// ---------------- W1 -> split bf16 hi/lo, row-major + transpose (proven) ------------
__global__ __launch_bounds__(256) void k_prep(const float* __restrict__ W1,
                                              ushortT* __restrict__ W1h,
                                              ushortT* __restrict__ W1l,
                                              ushortT* __restrict__ W1Th,
                                              ushortT* __restrict__ W1Tl) {
    __shared__ float tile[64][65];
    const int ti = blockIdx.x >> 3, tj = blockIdx.x & 7;
    const int t = threadIdx.x;
#pragma unroll
    for (int q = 0; q < 16; ++q) {
        int rr = q * 4 + (t >> 6), cc = t & 63;
        float v = W1[(size_t)(ti * 64 + rr) * 512 + tj * 64 + cc];
        tile[rr][cc] = v;
        ushortT h, l; split2(v, h, l);
        W1h[(size_t)(ti * 64 + rr) * 512 + tj * 64 + cc] = h;
        W1l[(size_t)(ti * 64 + rr) * 512 + tj * 64 + cc] = l;
    }
    __syncthreads();
#pragma unroll
    for (int q = 0; q < 16; ++q) {
        int rr = q * 4 + (t >> 6), cc = t & 63;
        ushortT h, l; split2(tile[cc][rr], h, l);
        W1Th[(size_t)(tj * 64 + rr) * 512 + ti * 64 + cc] = h;
        W1Tl[(size_t)(tj * 64 + rr) * 512 + ti * 64 + cc] = l;
    }
}

// ---------------- c2 = rho(x) @ W2^T + b2 via split-bf16 MFMA (proven) ----------------
__global__ __launch_bounds__(256) void k_c2(const float* __restrict__ x,
                                            const float* __restrict__ W2,
                                            const float* __restrict__ b2,
                                            float* __restrict__ c2) {
    __shared__ u32x4 cs[2048];
    u32x4* xHi = cs;
    u32x4* xLo = cs + 512;
    u32x4* wHi = cs + 1024;
    u32x4* wLo = cs + 1536;
    const int bid = blockIdx.x, t = threadIdx.x;
    const int lane = t & 63, w = t >> 6, l15 = lane & 15, l4 = lane >> 4;
    const int bm2 = (bid >> 3) * 64, bn2 = (bid & 7) * 64;
    const int mB2 = (w >> 1) * 32, nB2 = (w & 1) * 32;
    const int sr2 = t >> 2, ub = (t & 3) * 2;
    f32x4 accC[2][2];
#pragma unroll
    for (int i = 0; i < 2; ++i)
#pragma unroll
        for (int j = 0; j < 2; ++j) { f32x4 z = {0.f, 0.f, 0.f, 0.f}; accC[i][j] = z; }
    for (int k0 = 0; k0 < 784; k0 += 64) {
#pragma unroll
        for (int j = 0; j < 2; ++j) {
            int u = ub + j;
            bool valid = (k0 + u * 8 + 8 <= 784);
            union { ushortT us[8]; u32x4 v; } ph, pl, qh, ql;
            if (valid) {
                const float* srcx = x  + (size_t)(bm2 + sr2) * 784 + k0 + u * 8;
                const float* srcw = W2 + (size_t)(bn2 + sr2) * 784 + k0 + u * 8;
#pragma unroll
                for (int e = 0; e < 8; ++e) {
                    float cx = fminf(fmaxf(srcx[e], 0.f), 1.f);
                    split2(cx, ph.us[e], pl.us[e]);
                    split2(srcw[e], qh.us[e], ql.us[e]);
                }
            } else {
#pragma unroll
                for (int e = 0; e < 8; ++e) { ph.us[e]=0; pl.us[e]=0; qh.us[e]=0; ql.us[e]=0; }
            }
            int sw = u ^ (sr2 & 7);
            xHi[sr2 * 8 + sw] = ph.v;  xLo[sr2 * 8 + sw] = pl.v;
            wHi[sr2 * 8 + sw] = qh.v;  wLo[sr2 * 8 + sw] = ql.v;
        }
        __syncthreads();
        int kwMax = (k0 == 768) ? 1 : 2;
        for (int kw = 0; kw < kwMax; ++kw) {
            bf16x8 ah[2], al[2], bh[2], bl[2];
#pragma unroll
            for (int i = 0; i < 2; ++i) {
                int m = mB2 + i * 16 + l15;
                int uu = (kw * 4 + l4) ^ (m & 7);
                ah[i] = BCAST(xHi[m * 8 + uu]);
                al[i] = BCAST(xLo[m * 8 + uu]);
                int n = nB2 + i * 16 + l15;
                int uv = (kw * 4 + l4) ^ (n & 7);
                bh[i] = BCAST(wHi[n * 8 + uv]);
                bl[i] = BCAST(wLo[n * 8 + uv]);
            }
#pragma unroll
            for (int i = 0; i < 2; ++i)
#pragma unroll
                for (int jj = 0; jj < 2; ++jj) {
                    accC[i][jj] = MFMA(ah[i], bh[jj], accC[i][jj]);
                    accC[i][jj] = MFMA(al[i], bh[jj], accC[i][jj]);
                    accC[i][jj] = MFMA(ah[i], bl[jj], accC[i][jj]);
                }
        }
        __syncthreads();
    }
#pragma unroll
    for (int mi = 0; mi < 2; ++mi)
#pragma unroll
        for (int ni = 0; ni < 2; ++ni)
#pragma unroll
            for (int q = 0; q < 4; ++q) {
                int row = bm2 + mB2 + mi * 16 + l4 * 4 + q;
                int col = bn2 + nB2 + ni * 16 + l15;
                c2[(size_t)row * 512 + col] = accC[mi][ni][q] + b2[col];
            }
}

// ---------------- per-step fused kernel: 1024 blocks of 64x64 ----------------
// z1 blocks (role 0): new s1 tile;  z2 blocks (role 1): new s2 tile; z2&bn0 also z0.
// XCD affinity: panel = xcd*8 + p_local -> all consumers of a 64-row panel share an XCD.
__global__ __launch_bounds__(256, 4) void k_step3(const ushortT* __restrict__ sH,
                                                  ushortT* __restrict__ dH,
                                                  const ushortT* __restrict__ W1h,
                                                  const ushortT* __restrict__ W1l,
                                                  const ushortT* __restrict__ W1Th,
                                                  const ushortT* __restrict__ W1Tl,
                                                  const float* __restrict__ W0,
                                                  const float* __restrict__ b0,
                                                  const float* __restrict__ b1,
                                                  const float* __restrict__ c2,
                                                  float* __restrict__ outF) {
    __shared__ u32x4 smem[2560];     // 40 KiB -> 4 blocks/CU
    u32x4* AsR = smem;               //  512: A tile [64 rows][8 units], swizzled
    u32x4* BhS = smem + 512;         //  512: W-hi tile [64][8]
    u32x4* BlS = smem + 1024;        //  512: W-lo tile [64][8]
    u32x4* aux = smem + 1536;        // 1024: doZ0 -> Bz0[16][64]; z1 -> Bs2[0..255]+As2[256..511]

    const int bid = blockIdx.x, t = threadIdx.x;
    const int lane = t & 63, w = t >> 6, l15 = lane & 15, l4 = lane >> 4;
    const int mB = w * 16;           // wave rows [mB, mB+16)

    const int xcd = bid & 7, idx = bid >> 3;
    const int bn_i = idx & 7, role = (idx >> 3) & 1, pl = idx >> 4;
    const int panel = xcd * 8 + pl;
    const int bm = panel * 64, bn = bn_i * 64;
    const bool isZ1 = (role == 0);
    const bool doZ0 = (!isZ1) && (bn_i == 0);

    const int aOff = isZ1 ? OFF2B : OFF1B;   // z1 reads s2, z2 reads s1
    const int dOff = isZ1 ? OFF1B : OFF2B;   // dest layer
    const int oOff = isZ1 ? 10 : 522;
    const ushortT* __restrict__ Wbh = isZ1 ? W1h : W1Th;
    const ushortT* __restrict__ Wbl = isZ1 ? W1l : W1Tl;
    const bool fin = (outF != nullptr);

    // ---- early scalar prefetch: bias/c2 tile + old-state tile into registers ----
    float biasR[4][4];   // [ni][q]
    float oldv[4][4];    // [ni][q]
#pragma unroll
    for (int ni = 0; ni < 4; ++ni) {
        int gc = bn + ni * 16 + l15;
        float b1v = isZ1 ? b1[gc] : 0.f;
#pragma unroll
        for (int q = 0; q < 4; ++q) {
            size_t row = (size_t)bm + mB + l4 * 4 + q;
            biasR[ni][q] = isZ1 ? b1v : c2[row * 512 + gc];
            oldv[ni][q] = b2f(sH[row * HSTR + dOff + gc]);
        }
    }
    float oldZ0[4];
    float b0v = 0.f;
    if (doZ0) {
        b0v = (l15 < 10) ? b0[l15] : 0.f;
#pragma unroll
        for (int q = 0; q < 4; ++q) {
            size_t row = (size_t)bm + mB + l4 * 4 + q;
            oldZ0[q] = (l15 < 10) ? b2f(sH[row * HSTR + l15]) : 0.f;
        }
    }

    // ---- aux LDS staging (published by the K-loop's first barrier) ----
    if (isZ1) {
        {   // Bs2[n][u]: B[n][k] = W0[k][bn+n], K=32 window (10 real); 1 unit/thread
            int n = t >> 2, u = t & 3;
            union { ushortT us[8]; u32x4 v; } pk;
#pragma unroll
            for (int e = 0; e < 8; ++e) {
                int k = u * 8 + e;
                pk.us[e] = (k < 10) ? f2b(W0[(size_t)k * 512 + bn + n]) : (ushortT)0;
            }
            aux[n * 4 + u] = pk.v;
        }
        if (t < 64) {   // As2[row][u]: s0 window, zero-padded to K=32
            union { ushortT us[16]; u32x4 v2[2]; } pk;
#pragma unroll
            for (int e = 0; e < 16; ++e) pk.us[e] = 0;
            const ushortT* sp = sH + (size_t)(bm + t) * HSTR;
#pragma unroll
            for (int e = 0; e < 10; ++e) pk.us[e] = sp[e];
            u32x4 z = {0u, 0u, 0u, 0u};
            aux[256 + t * 4 + 0] = pk.v2[0];
            aux[256 + t * 4 + 1] = pk.v2[1];
            aux[256 + t * 4 + 2] = z;
            aux[256 + t * 4 + 3] = z;
        }
    } else if (doZ0) {  // Bz0[c][64 units]: W0^T, 16 cols x K=512, swizzled
        int c = t >> 4, u0 = (t & 15) * 4;
#pragma unroll
        for (int j = 0; j < 4; ++j) {
            int U = u0 + j;
            union { ushortT us[8]; u32x4 v; } pk;
#pragma unroll
            for (int e = 0; e < 8; ++e)
                pk.us[e] = (c < 10) ? f2b(W0[(size_t)c * 512 + U * 8 + e]) : (ushortT)0;
            aux[c * 64 + ((U & ~7) | ((U & 7) ^ (c & 7)))] = pk.v;
        }
    }

    f32x4 acc[4], accZ;
#pragma unroll
    for (int ni = 0; ni < 4; ++ni) { f32x4 z = {0.f, 0.f, 0.f, 0.f}; acc[ni] = z; }
    { f32x4 z = {0.f, 0.f, 0.f, 0.f}; accZ = z; }

    const int sr = t >> 2, su = (t & 3) * 2;   // staging: 4 thr/row, 2 units each

    // ---- software-pipelined K loop: 8 iters of BK=64, reg-staged double buffer ----
    u32x4 rA[2][2], rBh[2][2], rBl[2][2];
    {
        const u32x4* gA = (const u32x4*)(sH + (size_t)(bm + sr) * HSTR + aOff);
        const u32x4* gh = (const u32x4*)(Wbh + (size_t)(bn + sr) * 512);
        const u32x4* gl = (const u32x4*)(Wbl + (size_t)(bn + sr) * 512);
#pragma unroll
        for (int j = 0; j < 2; ++j) {
            rA[0][j] = gA[su + j];
            rBh[0][j] = gh[su + j];
            rBl[0][j] = gl[su + j];
        }
    }
#pragma unroll
    for (int it = 0; it < 8; ++it) {
        const int k0 = it * 64;
        const int cur = it & 1, nxt = cur ^ 1;
        __syncthreads();                      // prev compute done; LDS reusable
#pragma unroll
        for (int j = 0; j < 2; ++j) {
            int u = su + j;
            int sw = u ^ (sr & 7);
            AsR[sr * 8 + sw] = rA[cur][j];
            BhS[sr * 8 + sw] = rBh[cur][j];
            BlS[sr * 8 + sw] = rBl[cur][j];
        }
        if (it < 7) {                         // prefetch next K tile into regs
            const int k1 = k0 + 64;
            const u32x4* gA = (const u32x4*)(sH + (size_t)(bm + sr) * HSTR + aOff + k1);
            const u32x4* gh = (const u32x4*)(Wbh + (size_t)(bn + sr) * 512 + k1);
            const u32x4* gl = (const u32x4*)(Wbl + (size_t)(bn + sr) * 512 + k1);
#pragma unroll
            for (int j = 0; j < 2; ++j) {
                rA[nxt][j] = gA[su + j];
                rBh[nxt][j] = gh[su + j];
                rBl[nxt][j] = gl[su + j];
            }
        }
        __syncthreads();                      // publish LDS
#pragma unroll
        for (int kw = 0; kw < 2; ++kw) {
            bf16x8 a, bh[4], bl[4];
            {
                int m = mB + l15;
                a = BCAST(AsR[m * 8 + ((kw * 4 + l4) ^ (m & 7))]);
            }
#pragma unroll
            for (int ni = 0; ni < 4; ++ni) {
                int n = ni * 16 + l15;
                int u = (kw * 4 + l4) ^ (n & 7);
                bh[ni] = BCAST(BhS[n * 8 + u]);
                bl[ni] = BCAST(BlS[n * 8 + u]);
            }
#pragma unroll
            for (int ni = 0; ni < 4; ++ni) {
                acc[ni] = MFMA(a, bh[ni], acc[ni]);
                acc[ni] = MFMA(a, bl[ni], acc[ni]);
            }
            if (doZ0) {
                int U = it * 8 + kw * 4 + l4;
                bf16x8 bz = BCAST(aux[l15 * 64 + ((U & ~7) | ((U & 7) ^ (l15 & 7)))]);
                accZ = MFMA(a, bz, accZ);
            }
        }
    }
    if (isZ1) {   // s0 @ W0 extra K=32 window
        bf16x8 a2 = BCAST(aux[256 + (size_t)(mB + l15) * 4 + l4]);
#pragma unroll
        for (int ni = 0; ni < 4; ++ni) {
            bf16x8 bb = BCAST(aux[(size_t)(ni * 16 + l15) * 4 + l4]);
            acc[ni] = MFMA(a2, bb, acc[ni]);
        }
    }

    // ---- epilogue: v = clip(0.5*old(reg) + 0.5*(acc + bias(reg))) ----
    __syncthreads();   // all LDS reads done; AsR reusable as output staging
    if (fin) {
#pragma unroll
        for (int ni = 0; ni < 4; ++ni) {
            int gc = bn + ni * 16 + l15;
#pragma unroll
            for (int q = 0; q < 4; ++q) {
                float v = 0.5f * oldv[ni][q] + 0.5f * (acc[ni][q] + biasR[ni][q]);
                v = fminf(fmaxf(v, 0.f), 1.f);
                size_t row = (size_t)bm + mB + l4 * 4 + q;
                outF[row * CSTR + oOff + gc] = v;
            }
        }
        if (doZ0 && l15 < 10) {
#pragma unroll
            for (int q = 0; q < 4; ++q) {
                float v = 0.5f * oldZ0[q] + 0.5f * (accZ[q] + b0v);
                v = fminf(fmaxf(v, 0.f), 1.f);
                size_t row = (size_t)bm + mB + l4 * 4 + q;
                outF[row * CSTR + l15] = v;
            }
        }
    } else {
        ushortT* dlds = (ushortT*)AsR;   // 64x64 bf16 output tile
#pragma unroll
        for (int ni = 0; ni < 4; ++ni) {
#pragma unroll
            for (int q = 0; q < 4; ++q) {
                float v = 0.5f * oldv[ni][q] + 0.5f * (acc[ni][q] + biasR[ni][q]);
                v = fminf(fmaxf(v, 0.f), 1.f);
                dlds[(mB + l4 * 4 + q) * 64 + ni * 16 + l15] = f2b(v);
            }
        }
        if (doZ0 && l15 < 10) {
#pragma unroll
            for (int q = 0; q < 4; ++q) {
                float v = 0.5f * oldZ0[q] + 0.5f * (accZ[q] + b0v);
                v = fminf(fmaxf(v, 0.f), 1.f);
                size_t row = (size_t)bm + mB + l4 * 4 + q;
                dH[row * HSTR + l15] = f2b(v);
            }
        }
        __syncthreads();
        // coalesced 16B-per-lane tile store into this block's column slice
#pragma unroll
        for (int j = 0; j < 2; ++j) {
            int i = j * 256 + t;
            int row = i >> 3, u = i & 7;
            ((u32x4*)(dH + (size_t)(bm + row) * HSTR + dOff + bn))[u] = AsR[i];
        }
    }
}

extern "C" void kernel_launch(void* const* d_in, const int* in_sizes, int n_in,
                              void* d_out, int out_size, void* d_ws, size_t ws_size,
                              hipStream_t stream) {
    const float* x  = (const float*)d_in[3];
    const float* W0 = (const float*)d_in[4];
    const float* b0 = (const float*)d_in[5];
    const float* W1 = (const float*)d_in[6];
    const float* b1 = (const float*)d_in[7];
    const float* W2 = (const float*)d_in[8];
    const float* b2 = (const float*)d_in[9];

    // buffer A in d_out: 4096*1056*2 = 8,650,752 B <= 16,943,104 B
    ushortT* hiA = (ushortT*)d_out;
    // ws: hiB | c2 f32 | W1h | W1l | W1Th | W1Tl  (~19.1 MB)
    ushortT* hiB = (ushortT*)d_ws;
    float*   c2  = (float*)(hiB + (size_t)4096 * HSTR);
    ushortT* W1h = (ushortT*)(c2 + (size_t)4096 * 512);
    ushortT* W1l  = W1h + 512 * 512;
    ushortT* W1Th = W1l + 512 * 512;
    ushortT* W1Tl = W1Th + 512 * 512;

    const int zeroN = (int)((size_t)4096 * HSTR * sizeof(ushortT) / sizeof(u32x4));
    k_zero<<<1024, 256, 0, stream>>>((u32x4*)hiA, zeroN);
    k_prep<<<64, 256, 0, stream>>>(W1, W1h, W1l, W1Th, W1Tl);
    k_c2<<<512, 256, 0, stream>>>(x, W2, b2, c2);

    for (int ts = 0; ts < 30; ++ts) {
        const ushortT* sH = (ts & 1) ? hiB : hiA;
        ushortT* dH       = (ts & 1) ? hiA : hiB;
        float* outF = (ts == 29) ? (float*)d_out : nullptr;
        k_step3<<<1024, 256, 0, stream>>>(sH, dH, W1h, W1l, W1Th, W1Tl,
                                          W0, b0, b1, c2, outF);
    }
}